// Round 9
// baseline (711.137 us; speedup 1.0000x reference)
//
#include <hip/hip_runtime.h>

#define TLEN 8192
#define DD   4096
#define NF   10
#define NC   12        // 10 a_f coeffs + g + pad
#define NACC 12        // x_sum, pooled, h_f (f=0..9)
#define CCH  128       // chunks
#define ROWS 64        // TLEN / CCH

// ---------- helpers ----------
__device__ __forceinline__ double powi_d(double w, int n) {
    double a = 1.0, p = w;
    while (n) { if (n & 1) a *= p; p *= p; n >>= 1; }
    return a;
}

// ---------- kernel 1: pass with per-block coef prologue (R8-identical) ------
__global__ __launch_bounds__(256) void pass_kernel(const float* __restrict__ inp,
                                                   const float* __restrict__ w,
                                                   const float* __restrict__ pool_w,
                                                   float* __restrict__ part) {
    __shared__ float sc [ROWS * NC];
    __shared__ float scg[ROWS * NF];
    const int ch = blockIdx.y;
    const int t0 = ch * ROWS;

    for (int i = threadIdx.x; i < ROWS * NF; i += 256) {
        int r = i / NF, f = i - r * NF;
        double wf = (double)w[(size_t)f * DD];   // broadcast along D
        int n = TLEN - 1 - (t0 + r);
        double a = powi_d(wf, n);
        double den = 1.0 - wf;
        sc[r * NC + f] = (float)a;
        scg[i] = (float)((den > 1e-30) ? (double)pool_w[f] * (1.0 - a) / den
                                       : (double)pool_w[f] * (double)n);
    }
    __syncthreads();
    if (threadIdx.x < ROWS) {
        float g = 0.0f;
#pragma unroll
        for (int f = 0; f < NF; ++f) g += scg[threadIdx.x * NF + f];
        sc[threadIdx.x * NC + NF] = g;
    }
    __syncthreads();

    const int d = blockIdx.x * 1024 + threadIdx.x * 4;
    float sx=0,sy=0,sz=0,sw=0;           // x_sum
    float px=0,py=0,pz=0,pw4=0;          // pooled_raw
    float hx[NF], hy[NF], hz[NF], hw[NF];
#pragma unroll
    for (int f = 0; f < NF; ++f) { hx[f]=0; hy[f]=0; hz[f]=0; hw[f]=0; }

    const float* ip = inp + (size_t)t0 * DD + d;
    for (int r = 0; r < ROWS; ++r) {
        float4 x = *(const float4*)ip;
        ip += DD;
        const float* cf = &sc[r * NC];
        sx += x.x; sy += x.y; sz += x.z; sw += x.w;
        float g = cf[NF];
        px  = fmaf(g, x.x, px);  py  = fmaf(g, x.y, py);
        pz  = fmaf(g, x.z, pz);  pw4 = fmaf(g, x.w, pw4);
#pragma unroll
        for (int f = 0; f < NF; ++f) {
            float a = cf[f];
            hx[f] = fmaf(a, x.x, hx[f]); hy[f] = fmaf(a, x.y, hy[f]);
            hz[f] = fmaf(a, x.z, hz[f]); hw[f] = fmaf(a, x.w, hw[f]);
        }
    }

    size_t base = ((size_t)ch * NACC) * DD + d;
    *(float4*)(part + base)      = make_float4(sx, sy, sz, sw);
    *(float4*)(part + base + DD) = make_float4(px, py, pz, pw4);
#pragma unroll
    for (int f = 0; f < NF; ++f)
        *(float4*)(part + base + (size_t)(2 + f) * DD) =
            make_float4(hx[f], hy[f], hz[f], hw[f]);
}

// ---------- kernel 2: reduce + finalize fused (R8-identical) ----------------
__global__ __launch_bounds__(256) void redfin_kernel(const float* __restrict__ part,
                                                     const float* __restrict__ w,
                                                     const float* __restrict__ pool_w,
                                                     const float* __restrict__ pool_b,
                                                     const float* __restrict__ hidden,
                                                     float* __restrict__ out,
                                                     float* __restrict__ avg) {
    __shared__ float swT[NF], spwsT[NF];
    if (threadIdx.x < NF) {
        int f = threadIdx.x;
        double wf = (double)w[(size_t)f * DD];
        double wTd = powi_d(wf, TLEN);
        double den = 1.0 - wf;
        double sTd = (den > 1e-30) ? (1.0 - wTd) / den : (double)TLEN;
        swT[f]   = (float)wTd;
        spwsT[f] = (float)((double)pool_w[f] * sTd);
    }
    __syncthreads();

    const int idx = blockIdx.x * 256 + threadIdx.x;
    const int acc = idx >> 12;          // 0..11 (uniform per block)
    const int d   = idx & (DD - 1);

    float s0=0,s1=0,s2=0,s3=0,s4=0,s5=0,s6=0,s7=0;
#pragma unroll
    for (int c = 0; c < CCH; c += 8) {
        s0 += part[(size_t)(c+0) * (NACC*DD) + idx];
        s1 += part[(size_t)(c+1) * (NACC*DD) + idx];
        s2 += part[(size_t)(c+2) * (NACC*DD) + idx];
        s3 += part[(size_t)(c+3) * (NACC*DD) + idx];
        s4 += part[(size_t)(c+4) * (NACC*DD) + idx];
        s5 += part[(size_t)(c+5) * (NACC*DD) + idx];
        s6 += part[(size_t)(c+6) * (NACC*DD) + idx];
        s7 += part[(size_t)(c+7) * (NACC*DD) + idx];
    }
    float s = ((s0+s1)+(s2+s3)) + ((s4+s5)+(s6+s7));

    const float invT = 1.0f / (float)TLEN;
    if (acc == 0) {
        avg[d] = s * invT;
    } else if (acc == 1) {
        float corr = 0.0f;
#pragma unroll
        for (int f = 0; f < NF; ++f)
            corr = fmaf(spwsT[f], hidden[(size_t)f * DD + d], corr);
        avg[DD + d] = (s + corr) * invT + pool_b[0];
    } else {
        int f = acc - 2;
        out[10 + (size_t)f * DD + d] = fmaf(swT[f], hidden[(size_t)f * DD + d], s);
    }
}

// ---------- kernel 3: GEMV (R8-identical) ----------
__global__ __launch_bounds__(256) void gemv_kernel(const float* __restrict__ W,
                                                   const float* __restrict__ b,
                                                   const float* __restrict__ avg,
                                                   float* __restrict__ hid) {
    int row  = blockIdx.x * 4 + (threadIdx.x >> 6);
    int lane = threadIdx.x & 63;
    const float* wr = W + (size_t)row * (2 * DD);
    float acc = 0.0f;
#pragma unroll 8
    for (int j0 = 0; j0 < 32; ++j0) {
        int j = j0 * 256 + lane * 4;
        float4 wv = *(const float4*)(wr + j);
        float4 av = *(const float4*)(avg + j);
        acc = fmaf(wv.x, av.x, acc); acc = fmaf(wv.y, av.y, acc);
        acc = fmaf(wv.z, av.z, acc); acc = fmaf(wv.w, av.w, acc);
    }
    for (int off = 32; off; off >>= 1) acc += __shfl_down(acc, off, 64);
    if (lane == 0) hid[row] = fmaxf(acc + b[row], 0.0f);
}

// ---------- kernel 4: final 10-way dot (R8-identical) ----------
__global__ void out_kernel(const float* __restrict__ hid,
                           const float* __restrict__ ow,
                           const float* __restrict__ ob,
                           float* __restrict__ out) {
    __shared__ float redl[256];
    int o = blockIdx.x;
    float acc = 0.0f;
    for (int h = threadIdx.x; h < DD; h += 256)
        acc = fmaf(hid[h], ow[(size_t)o * DD + h], acc);
    redl[threadIdx.x] = acc;
    __syncthreads();
    for (int s = 128; s; s >>= 1) {
        if (threadIdx.x < s) redl[threadIdx.x] += redl[threadIdx.x + s];
        __syncthreads();
    }
    if (threadIdx.x == 0) out[o] = redl[0] + ob[o];
}

// ---------- diagnostic no-op (measures per-node transition cost) ----------
__global__ void nop_kernel() {}

extern "C" void kernel_launch(void* const* d_in, const int* in_sizes, int n_in,
                              void* d_out, int out_size, void* d_ws, size_t ws_size,
                              hipStream_t stream) {
    const float* inp    = (const float*)d_in[0];
    const float* hidden = (const float*)d_in[1];
    const float* w      = (const float*)d_in[2];
    const float* pw     = (const float*)d_in[3];
    const float* pb     = (const float*)d_in[4];
    const float* i2o_w  = (const float*)d_in[5];
    const float* i2o_b  = (const float*)d_in[6];
    const float* o_w    = (const float*)d_in[7];
    const float* o_b    = (const float*)d_in[8];
    float* out = (float*)d_out;
    float* ws  = (float*)d_ws;

    float* avg  = ws;                  // 8192
    float* hid  = ws + 8192;           // 4096
    float* part = ws + 12288;          // 128*12*4096 floats (25 MB)

    // DIAGNOSTIC ROUND (all duplicates idempotent; output unchanged):
    // 10x alternating pass->redfin pairs: every redfin rep reads a freshly
    // re-dirtied `part` (reproduces steady-state cross-XCD dirty-read cost).
    //   delta_pairs = 9*(T_pass_warm + T_redfin_dirty + 2g)
    // 16x no-op nodes: delta_nops = 16*(g + eps).
    // Pre-committed readings: dur ~470 (g,Tr small) / ~810 (Tr~48) /
    //                         ~1060 (g~19) / ~1400 (both).
    pass_kernel  <<<dim3(4, CCH), 256, 0, stream>>>(inp, w, pw, part);
    redfin_kernel<<<192, 256, 0, stream>>>(part, w, pw, pb, hidden, out, avg);
    for (int i = 0; i < 9; ++i) {
        pass_kernel  <<<dim3(4, CCH), 256, 0, stream>>>(inp, w, pw, part);
        redfin_kernel<<<192, 256, 0, stream>>>(part, w, pw, pb, hidden, out, avg);
    }
    for (int i = 0; i < 16; ++i)
        nop_kernel<<<1, 64, 0, stream>>>();
    gemv_kernel  <<<DD / 4, 256, 0, stream>>>(i2o_w, i2o_b, avg, hid);
    out_kernel   <<<10, 256, 0, stream>>>(hid, o_w, o_b, out);
}

// Round 10
// 527.173 us; speedup vs baseline: 1.3490x; 1.3490x over previous
//
#include <hip/hip_runtime.h>

#define TLEN 8192
#define DD   4096
#define NF   10
#define NC   12        // 10 a_f coeffs + g + pad
#define NACC 12        // x_sum, pooled, h_f (f=0..9)
#define CCH  128       // chunks
#define ROWS 64        // TLEN / CCH
#define NBLK 512       // megakernel grid (2 blocks/CU on 256 CUs)
#define H1   4096      // i2o rows

// ---------- helpers ----------
__device__ __forceinline__ double powi_d(double w, int n) {
    double a = 1.0, p = w;
    while (n) { if (n & 1) a *= p; p *= p; n >>= 1; }
    return a;
}

// ---------- megakernel: pass | gate | redfin | gate | gemv | elect-last: out --
__global__ __launch_bounds__(256, 2) void mega_kernel(
    const float* __restrict__ inp,   const float* __restrict__ hidden,
    const float* __restrict__ w,     const float* __restrict__ pool_w,
    const float* __restrict__ pool_b,
    const float* __restrict__ W1,    const float* __restrict__ b1,
    const float* __restrict__ W2,    const float* __restrict__ b2,
    float* __restrict__ out,
    unsigned int* __restrict__ cnt,  // [0],[1],[2] zeroed by memset node
    float* __restrict__ avg, float* __restrict__ hid, float* __restrict__ part)
{
    __shared__ float sc [ROWS * NC];
    __shared__ float scg[ROWS * NF];
    __shared__ float redl[256];
    __shared__ unsigned int ticket;

    const int tid = threadIdx.x;
    const int bid = blockIdx.x;

    // ================= phase A: pass (R8-identical body) =================
    {
        const int cgp = bid & 3;        // column quarter
        const int ch  = bid >> 2;       // chunk 0..127
        const int t0  = ch * ROWS;

        for (int i = tid; i < ROWS * NF; i += 256) {
            int r = i / NF, f = i - r * NF;
            double wf = (double)w[(size_t)f * DD];
            int n = TLEN - 1 - (t0 + r);
            double a = powi_d(wf, n);
            double den = 1.0 - wf;
            sc[r * NC + f] = (float)a;
            scg[i] = (float)((den > 1e-30) ? (double)pool_w[f] * (1.0 - a) / den
                                           : (double)pool_w[f] * (double)n);
        }
        __syncthreads();
        if (tid < ROWS) {
            float g = 0.0f;
#pragma unroll
            for (int f = 0; f < NF; ++f) g += scg[tid * NF + f];
            sc[tid * NC + NF] = g;
        }
        __syncthreads();

        const int d = cgp * 1024 + tid * 4;
        float sx=0,sy=0,sz=0,sw=0, px=0,py=0,pz=0,pw4=0;
        float hx[NF], hy[NF], hz[NF], hw[NF];
#pragma unroll
        for (int f = 0; f < NF; ++f) { hx[f]=0; hy[f]=0; hz[f]=0; hw[f]=0; }

        const float* ip = inp + (size_t)t0 * DD + d;
        for (int r = 0; r < ROWS; ++r) {
            float4 x = *(const float4*)ip;
            ip += DD;
            const float* cf = &sc[r * NC];
            sx += x.x; sy += x.y; sz += x.z; sw += x.w;
            float g = cf[NF];
            px  = fmaf(g, x.x, px);  py  = fmaf(g, x.y, py);
            pz  = fmaf(g, x.z, pz);  pw4 = fmaf(g, x.w, pw4);
#pragma unroll
            for (int f = 0; f < NF; ++f) {
                float a = cf[f];
                hx[f] = fmaf(a, x.x, hx[f]); hy[f] = fmaf(a, x.y, hy[f]);
                hz[f] = fmaf(a, x.z, hz[f]); hw[f] = fmaf(a, x.w, hw[f]);
            }
        }
        size_t base = ((size_t)ch * NACC) * DD + d;
        *(float4*)(part + base)      = make_float4(sx, sy, sz, sw);
        *(float4*)(part + base + DD) = make_float4(px, py, pz, pw4);
#pragma unroll
        for (int f = 0; f < NF; ++f)
            *(float4*)(part + base + (size_t)(2 + f) * DD) =
                make_float4(hx[f], hy[f], hz[f], hw[f]);
    }

    // ---- gate 0: all part writes visible device-wide ----
    __threadfence();                 // release: drain + L2 writeback
    __syncthreads();
    if (tid == 0) {
        __hip_atomic_fetch_add(&cnt[0], 1u, __ATOMIC_RELEASE, __HIP_MEMORY_SCOPE_AGENT);
        while (__hip_atomic_load(&cnt[0], __ATOMIC_RELAXED, __HIP_MEMORY_SCOPE_AGENT) < NBLK)
            __builtin_amdgcn_s_sleep(1);
    }
    __syncthreads();
    __threadfence();                 // acquire: invalidate stale lines

    // ================= phase B: redfin (blocks 0..191, R8 body) ============
    if (bid < 192) {
        if (tid < NF) {
            int f = tid;
            double wf = (double)w[(size_t)f * DD];
            double wTd = powi_d(wf, TLEN);
            double den = 1.0 - wf;
            double sTd = (den > 1e-30) ? (1.0 - wTd) / den : (double)TLEN;
            sc[f]      = (float)wTd;                         // swT
            sc[NF + f] = (float)((double)pool_w[f] * sTd);   // spwsT
        }
        __syncthreads();

        const int idx = bid * 256 + tid;
        const int acc = idx >> 12;
        const int d   = idx & (DD - 1);

        float s0=0,s1=0,s2=0,s3=0,s4=0,s5=0,s6=0,s7=0;
#pragma unroll
        for (int c = 0; c < CCH; c += 8) {
            s0 += part[(size_t)(c+0) * (NACC*DD) + idx];
            s1 += part[(size_t)(c+1) * (NACC*DD) + idx];
            s2 += part[(size_t)(c+2) * (NACC*DD) + idx];
            s3 += part[(size_t)(c+3) * (NACC*DD) + idx];
            s4 += part[(size_t)(c+4) * (NACC*DD) + idx];
            s5 += part[(size_t)(c+5) * (NACC*DD) + idx];
            s6 += part[(size_t)(c+6) * (NACC*DD) + idx];
            s7 += part[(size_t)(c+7) * (NACC*DD) + idx];
        }
        float s = ((s0+s1)+(s2+s3)) + ((s4+s5)+(s6+s7));

        const float invT = 1.0f / (float)TLEN;
        if (acc == 0) {
            avg[d] = s * invT;
        } else if (acc == 1) {
            float corr = 0.0f;
#pragma unroll
            for (int f = 0; f < NF; ++f)
                corr = fmaf(sc[NF + f], hidden[(size_t)f * DD + d], corr);
            avg[DD + d] = (s + corr) * invT + pool_b[0];
        } else {
            int f = acc - 2;
            out[10 + (size_t)f * DD + d] = fmaf(sc[f], hidden[(size_t)f * DD + d], s);
        }
    }

    // ---- gate 1: avg visible device-wide ----
    __threadfence();
    __syncthreads();
    if (tid == 0) {
        __hip_atomic_fetch_add(&cnt[1], 1u, __ATOMIC_RELEASE, __HIP_MEMORY_SCOPE_AGENT);
        while (__hip_atomic_load(&cnt[1], __ATOMIC_RELAXED, __HIP_MEMORY_SCOPE_AGENT) < NBLK)
            __builtin_amdgcn_s_sleep(1);
    }
    __syncthreads();
    __threadfence();

    // ================= phase C: gemv (8 rows per block, 2 per wave) =========
    {
        const int wave = tid >> 6, lane = tid & 63;
#pragma unroll
        for (int rr = 0; rr < 2; ++rr) {
            int row = bid * 8 + wave * 2 + rr;
            const float* wr = W1 + (size_t)row * (2 * DD) + lane * 4;
            const float* ar = avg + lane * 4;
            float acc = 0.0f;
#pragma unroll 8
            for (int j0 = 0; j0 < 32; ++j0) {
                float4 wv = *(const float4*)(wr + j0 * 256);
                float4 av = *(const float4*)(ar + j0 * 256);
                acc = fmaf(wv.x, av.x, acc); acc = fmaf(wv.y, av.y, acc);
                acc = fmaf(wv.z, av.z, acc); acc = fmaf(wv.w, av.w, acc);
            }
            for (int off = 32; off; off >>= 1) acc += __shfl_down(acc, off, 64);
            if (lane == 0) hid[row] = fmaxf(acc + b1[row], 0.0f);
        }
    }

    // ---- election: last block to finish gemv computes the 10 outputs ------
    __threadfence();                 // release hid
    __syncthreads();
    if (tid == 0)
        ticket = __hip_atomic_fetch_add(&cnt[2], 1u, __ATOMIC_ACQ_REL, __HIP_MEMORY_SCOPE_AGENT);
    __syncthreads();
    if (ticket == NBLK - 1) {
        __threadfence();             // acquire all hid writes
        for (int o = 0; o < 10; ++o) {
            float acc = 0.0f;
            for (int h = tid; h < H1; h += 256)
                acc = fmaf(hid[h], W2[(size_t)o * H1 + h], acc);
            redl[tid] = acc;
            __syncthreads();
            for (int s = 128; s; s >>= 1) {
                if (tid < s) redl[tid] += redl[tid + s];
                __syncthreads();
            }
            if (tid == 0) out[o] = redl[0] + b2[o];
            __syncthreads();
        }
    }
}

// =======================================================================
// Fallback: R8's proven 4-kernel pipeline (115 us) if cooperative launch fails
// =======================================================================
__global__ __launch_bounds__(256) void pass_kernel(const float* __restrict__ inp,
                                                   const float* __restrict__ w,
                                                   const float* __restrict__ pool_w,
                                                   float* __restrict__ part) {
    __shared__ float sc [ROWS * NC];
    __shared__ float scg[ROWS * NF];
    const int ch = blockIdx.y;
    const int t0 = ch * ROWS;
    for (int i = threadIdx.x; i < ROWS * NF; i += 256) {
        int r = i / NF, f = i - r * NF;
        double wf = (double)w[(size_t)f * DD];
        int n = TLEN - 1 - (t0 + r);
        double a = powi_d(wf, n);
        double den = 1.0 - wf;
        sc[r * NC + f] = (float)a;
        scg[i] = (float)((den > 1e-30) ? (double)pool_w[f] * (1.0 - a) / den
                                       : (double)pool_w[f] * (double)n);
    }
    __syncthreads();
    if (threadIdx.x < ROWS) {
        float g = 0.0f;
#pragma unroll
        for (int f = 0; f < NF; ++f) g += scg[threadIdx.x * NF + f];
        sc[threadIdx.x * NC + NF] = g;
    }
    __syncthreads();
    const int d = blockIdx.x * 1024 + threadIdx.x * 4;
    float sx=0,sy=0,sz=0,sw=0, px=0,py=0,pz=0,pw4=0;
    float hx[NF], hy[NF], hz[NF], hw[NF];
#pragma unroll
    for (int f = 0; f < NF; ++f) { hx[f]=0; hy[f]=0; hz[f]=0; hw[f]=0; }
    const float* ip = inp + (size_t)t0 * DD + d;
    for (int r = 0; r < ROWS; ++r) {
        float4 x = *(const float4*)ip; ip += DD;
        const float* cf = &sc[r * NC];
        sx += x.x; sy += x.y; sz += x.z; sw += x.w;
        float g = cf[NF];
        px  = fmaf(g, x.x, px);  py  = fmaf(g, x.y, py);
        pz  = fmaf(g, x.z, pz);  pw4 = fmaf(g, x.w, pw4);
#pragma unroll
        for (int f = 0; f < NF; ++f) {
            float a = cf[f];
            hx[f] = fmaf(a, x.x, hx[f]); hy[f] = fmaf(a, x.y, hy[f]);
            hz[f] = fmaf(a, x.z, hz[f]); hw[f] = fmaf(a, x.w, hw[f]);
        }
    }
    size_t base = ((size_t)ch * NACC) * DD + d;
    *(float4*)(part + base)      = make_float4(sx, sy, sz, sw);
    *(float4*)(part + base + DD) = make_float4(px, py, pz, pw4);
#pragma unroll
    for (int f = 0; f < NF; ++f)
        *(float4*)(part + base + (size_t)(2 + f) * DD) =
            make_float4(hx[f], hy[f], hz[f], hw[f]);
}

__global__ __launch_bounds__(256) void redfin_kernel(const float* __restrict__ part,
                                                     const float* __restrict__ w,
                                                     const float* __restrict__ pool_w,
                                                     const float* __restrict__ pool_b,
                                                     const float* __restrict__ hidden,
                                                     float* __restrict__ out,
                                                     float* __restrict__ avg) {
    __shared__ float swT[NF], spwsT[NF];
    if (threadIdx.x < NF) {
        int f = threadIdx.x;
        double wf = (double)w[(size_t)f * DD];
        double wTd = powi_d(wf, TLEN);
        double den = 1.0 - wf;
        double sTd = (den > 1e-30) ? (1.0 - wTd) / den : (double)TLEN;
        swT[f]   = (float)wTd;
        spwsT[f] = (float)((double)pool_w[f] * sTd);
    }
    __syncthreads();
    const int idx = blockIdx.x * 256 + threadIdx.x;
    const int acc = idx >> 12;
    const int d   = idx & (DD - 1);
    float s0=0,s1=0,s2=0,s3=0,s4=0,s5=0,s6=0,s7=0;
#pragma unroll
    for (int c = 0; c < CCH; c += 8) {
        s0 += part[(size_t)(c+0) * (NACC*DD) + idx];
        s1 += part[(size_t)(c+1) * (NACC*DD) + idx];
        s2 += part[(size_t)(c+2) * (NACC*DD) + idx];
        s3 += part[(size_t)(c+3) * (NACC*DD) + idx];
        s4 += part[(size_t)(c+4) * (NACC*DD) + idx];
        s5 += part[(size_t)(c+5) * (NACC*DD) + idx];
        s6 += part[(size_t)(c+6) * (NACC*DD) + idx];
        s7 += part[(size_t)(c+7) * (NACC*DD) + idx];
    }
    float s = ((s0+s1)+(s2+s3)) + ((s4+s5)+(s6+s7));
    const float invT = 1.0f / (float)TLEN;
    if (acc == 0) {
        avg[d] = s * invT;
    } else if (acc == 1) {
        float corr = 0.0f;
#pragma unroll
        for (int f = 0; f < NF; ++f)
            corr = fmaf(spwsT[f], hidden[(size_t)f * DD + d], corr);
        avg[DD + d] = (s + corr) * invT + pool_b[0];
    } else {
        int f = acc - 2;
        out[10 + (size_t)f * DD + d] = fmaf(swT[f], hidden[(size_t)f * DD + d], s);
    }
}

__global__ __launch_bounds__(256) void gemv_kernel(const float* __restrict__ W,
                                                   const float* __restrict__ b,
                                                   const float* __restrict__ avg,
                                                   float* __restrict__ hid) {
    int row  = blockIdx.x * 4 + (threadIdx.x >> 6);
    int lane = threadIdx.x & 63;
    const float* wr = W + (size_t)row * (2 * DD);
    float acc = 0.0f;
#pragma unroll 8
    for (int j0 = 0; j0 < 32; ++j0) {
        int j = j0 * 256 + lane * 4;
        float4 wv = *(const float4*)(wr + j);
        float4 av = *(const float4*)(avg + j);
        acc = fmaf(wv.x, av.x, acc); acc = fmaf(wv.y, av.y, acc);
        acc = fmaf(wv.z, av.z, acc); acc = fmaf(wv.w, av.w, acc);
    }
    for (int off = 32; off; off >>= 1) acc += __shfl_down(acc, off, 64);
    if (lane == 0) hid[row] = fmaxf(acc + b[row], 0.0f);
}

__global__ void out_kernel(const float* __restrict__ hid,
                           const float* __restrict__ ow,
                           const float* __restrict__ ob,
                           float* __restrict__ out) {
    __shared__ float redl[256];
    int o = blockIdx.x;
    float acc = 0.0f;
    for (int h = threadIdx.x; h < DD; h += 256)
        acc = fmaf(hid[h], ow[(size_t)o * DD + h], acc);
    redl[threadIdx.x] = acc;
    __syncthreads();
    for (int s = 128; s; s >>= 1) {
        if (threadIdx.x < s) redl[threadIdx.x] += redl[threadIdx.x + s];
        __syncthreads();
    }
    if (threadIdx.x == 0) out[o] = redl[0] + ob[o];
}

extern "C" void kernel_launch(void* const* d_in, const int* in_sizes, int n_in,
                              void* d_out, int out_size, void* d_ws, size_t ws_size,
                              hipStream_t stream) {
    const float* inp    = (const float*)d_in[0];
    const float* hidden = (const float*)d_in[1];
    const float* w      = (const float*)d_in[2];
    const float* pw     = (const float*)d_in[3];
    const float* pb     = (const float*)d_in[4];
    const float* i2o_w  = (const float*)d_in[5];
    const float* i2o_b  = (const float*)d_in[6];
    const float* o_w    = (const float*)d_in[7];
    const float* o_b    = (const float*)d_in[8];
    float* out = (float*)d_out;
    float* ws  = (float*)d_ws;

    unsigned int* cnt = (unsigned int*)ws;     // 3 counters in first 64 B
    float* avg  = ws + 16;                     // 8192
    float* hid  = ws + 16 + 8192;              // 4096
    float* part = ws + 16 + 8192 + 4096;       // 128*12*4096 floats (25 MB)

    // zero gate counters (nop-class node: ~free per R9)
    hipMemsetAsync(cnt, 0, 64, stream);

    void* args[] = {
        (void*)&inp, (void*)&hidden, (void*)&w, (void*)&pw, (void*)&pb,
        (void*)&i2o_w, (void*)&i2o_b, (void*)&o_w, (void*)&o_b,
        (void*)&out, (void*)&cnt, (void*)&avg, (void*)&hid, (void*)&part
    };
    hipError_t err = hipLaunchCooperativeKernel((const void*)mega_kernel,
                                                dim3(NBLK), dim3(256),
                                                args, 0, stream);
    if (err != hipSuccess) {
        // fallback: R8's proven 4-node pipeline
        pass_kernel  <<<dim3(4, CCH), 256, 0, stream>>>(inp, w, pw, part);
        redfin_kernel<<<192, 256, 0, stream>>>(part, w, pw, pb, hidden, out, avg);
        gemv_kernel  <<<H1 / 4, 256, 0, stream>>>(i2o_w, i2o_b, avg, hid);
        out_kernel   <<<10, 256, 0, stream>>>(hid, o_w, o_b, out);
    }
}